// Round 4
// baseline (307.281 us; speedup 1.0000x reference)
//
#include <hip/hip_runtime.h>

#define N_NODES 50000
#define N_EDGES 800000
#define NPAIRS  65536

// ---------------- CSR build ----------------

__global__ __launch_bounds__(256) void hist_kernel(const int* __restrict__ rows,
                                                   int* __restrict__ cnt, int n) {
    int e = blockIdx.x * 256 + threadIdx.x;
    if (e < n) atomicAdd(&cnt[rows[e]], 1);
}

__global__ __launch_bounds__(256) void scan_block_kernel(const int* __restrict__ cnt,
                                                         int* __restrict__ excl,
                                                         int* __restrict__ blksum, int n) {
    __shared__ int s[256];
    int tid = threadIdx.x;
    int i = blockIdx.x * 256 + tid;
    int v = (i < n) ? cnt[i] : 0;
    s[tid] = v; __syncthreads();
    for (int off = 1; off < 256; off <<= 1) {
        int t = (tid >= off) ? s[tid - off] : 0;
        __syncthreads();
        s[tid] += t;
        __syncthreads();
    }
    if (i < n) excl[i] = s[tid] - v;
    if (tid == 255) blksum[blockIdx.x] = s[255];
}

__global__ __launch_bounds__(256) void scan_sums_kernel(int* blksum, int nb) {
    __shared__ int s[256];
    int tid = threadIdx.x;
    int v = (tid < nb) ? blksum[tid] : 0;
    s[tid] = v; __syncthreads();
    for (int off = 1; off < 256; off <<= 1) {
        int t = (tid >= off) ? s[tid - off] : 0;
        __syncthreads();
        s[tid] += t;
        __syncthreads();
    }
    if (tid < nb) blksum[tid] = s[tid] - v;
}

__global__ __launch_bounds__(256) void scan_add_kernel(int* __restrict__ row_ptr,
                                                       const int* __restrict__ blksum,
                                                       int* __restrict__ cursor,
                                                       int n, int e_total) {
    int i = blockIdx.x * 256 + threadIdx.x;
    if (i < n) {
        int v = row_ptr[i] + blksum[blockIdx.x];
        row_ptr[i] = v;
        cursor[i] = v;
    }
    if (i == 0) row_ptr[n] = e_total;
}

__global__ __launch_bounds__(256) void scatter_kernel(const int* __restrict__ rows,
                                                      const int* __restrict__ cols,
                                                      const float* __restrict__ vals,
                                                      int* __restrict__ cursor,
                                                      int* __restrict__ csr_col,
                                                      float* __restrict__ csr_val, int n) {
    int e = blockIdx.x * 256 + threadIdx.x;
    if (e < n) {
        int r = rows[e];
        int pos = atomicAdd(&cursor[r], 1);
        csr_col[pos] = cols[e];
        csr_val[pos] = vals[e];
    }
}

// ---------------- GEMM1: y = (node_emb + type_emb[tid]) @ W1  [N,128]x[128,128] ----------------

__global__ __launch_bounds__(256) void gemm1_kernel(const float* __restrict__ node_emb,
                                                    const float* __restrict__ type_emb,
                                                    const int* __restrict__ tids,
                                                    const float* __restrict__ W1,
                                                    float* __restrict__ y) {
    __shared__ float As[32][32];
    __shared__ float Ws[32][128];
    int t = threadIdx.x;
    int tx = t & 31, ty = t >> 5;
    int row0 = blockIdx.x * 32;
    float acc[4][4] = {};
    int lrow = t >> 3, lk0 = (t & 7) << 2;
    int rg_l = row0 + lrow;
    for (int kc = 0; kc < 128; kc += 32) {
        float4 av = make_float4(0.f, 0.f, 0.f, 0.f);
        if (rg_l < N_NODES) {
            const float4 a = *(const float4*)(node_emb + (size_t)rg_l * 128 + kc + lk0);
            const float4 b = *(const float4*)(type_emb + (size_t)tids[rg_l] * 128 + kc + lk0);
            av = make_float4(a.x + b.x, a.y + b.y, a.z + b.z, a.w + b.w);
        }
        *(float4*)&As[lrow][lk0] = av;
#pragma unroll
        for (int l = 0; l < 4; l++) {
            int idx = l * 1024 + t * 4;
            int kk = idx >> 7, c = idx & 127;
            *(float4*)&Ws[kk][c] = *(const float4*)(W1 + (size_t)(kc + kk) * 128 + c);
        }
        __syncthreads();
#pragma unroll
        for (int kk = 0; kk < 32; kk++) {
            float4 w = *(const float4*)&Ws[kk][tx * 4];
#pragma unroll
            for (int i = 0; i < 4; i++) {
                float a = As[ty + 8 * i][kk];
                acc[i][0] += a * w.x; acc[i][1] += a * w.y;
                acc[i][2] += a * w.z; acc[i][3] += a * w.w;
            }
        }
        __syncthreads();
    }
#pragma unroll
    for (int i = 0; i < 4; i++) {
        int rg = row0 + ty + 8 * i;
        if (rg < N_NODES) {
            *(float4*)(y + (size_t)rg * 128 + tx * 4) =
                make_float4(acc[i][0], acc[i][1], acc[i][2], acc[i][3]);
        }
    }
}

// ---------------- GEMM2: g = h @ W2  [N,128]x[128,64] ----------------

__global__ __launch_bounds__(256) void gemm2_kernel(const float* __restrict__ h,
                                                    const float* __restrict__ W2,
                                                    float* __restrict__ g) {
    __shared__ float As[64][33];
    __shared__ float Ws[32][64];
    int t = threadIdx.x;
    int tx = t & 15, ty = t >> 4;
    int row0 = blockIdx.x * 64;
    float acc[4][4] = {};
    for (int kc = 0; kc < 128; kc += 32) {
#pragma unroll
        for (int l = 0; l < 2; l++) {
            int idx = l * 1024 + t * 4;
            int lrow = idx >> 5, lk0 = idx & 31;
            int rg = row0 + lrow;
            float4 v = make_float4(0.f, 0.f, 0.f, 0.f);
            if (rg < N_NODES) v = *(const float4*)(h + (size_t)rg * 128 + kc + lk0);
            As[lrow][lk0 + 0] = v.x; As[lrow][lk0 + 1] = v.y;
            As[lrow][lk0 + 2] = v.z; As[lrow][lk0 + 3] = v.w;
        }
#pragma unroll
        for (int l = 0; l < 2; l++) {
            int idx = l * 1024 + t * 4;
            int kk = idx >> 6, c = idx & 63;
            *(float4*)&Ws[kk][c] = *(const float4*)(W2 + (size_t)(kc + kk) * 64 + c);
        }
        __syncthreads();
#pragma unroll
        for (int kk = 0; kk < 32; kk++) {
            float4 w = *(const float4*)&Ws[kk][tx * 4];
#pragma unroll
            for (int i = 0; i < 4; i++) {
                float a = As[ty + 16 * i][kk];
                acc[i][0] += a * w.x; acc[i][1] += a * w.y;
                acc[i][2] += a * w.z; acc[i][3] += a * w.w;
            }
        }
        __syncthreads();
    }
#pragma unroll
    for (int i = 0; i < 4; i++) {
        int rg = row0 + ty + 16 * i;
        if (rg < N_NODES) {
            *(float4*)(g + (size_t)rg * 64 + tx * 4) =
                make_float4(acc[i][0], acc[i][1], acc[i][2], acc[i][3]);
        }
    }
}

// ---------------- SpMM (CSR, one wave per row) ----------------

template <int F, bool RELU>
__global__ __launch_bounds__(256) void spmm_kernel(const int* __restrict__ row_ptr,
                                                   const int* __restrict__ csr_col,
                                                   const float* __restrict__ csr_val,
                                                   const float* __restrict__ src,
                                                   const float* __restrict__ bias,
                                                   float* __restrict__ dst) {
    int wid = threadIdx.x >> 6, lane = threadIdx.x & 63;
    int row = blockIdx.x * 4 + wid;
    if (row >= N_NODES) return;
    int start = row_ptr[row], end = row_ptr[row + 1];
    if (F == 128) {
        float ax = 0.f, ay = 0.f;
        int c0 = lane * 2;
        for (int base = start; base < end; base += 64) {
            int idx = base + lane;
            int c = 0; float v = 0.f;
            if (idx < end) { c = csr_col[idx]; v = csr_val[idx]; }
            int cnt = min(64, end - base);
            for (int j = 0; j < cnt; j++) {
                int cc = __shfl(c, j);
                float vv = __shfl(v, j);
                const float2 s = *(const float2*)(src + (size_t)cc * 128 + c0);
                ax += vv * s.x; ay += vv * s.y;
            }
        }
        ax += bias[c0]; ay += bias[c0 + 1];
        if (RELU) { ax = fmaxf(ax, 0.f); ay = fmaxf(ay, 0.f); }
        *(float2*)(dst + (size_t)row * 128 + c0) = make_float2(ax, ay);
    } else {
        float a = 0.f;
        for (int base = start; base < end; base += 64) {
            int idx = base + lane;
            int c = 0; float v = 0.f;
            if (idx < end) { c = csr_col[idx]; v = csr_val[idx]; }
            int cnt = min(64, end - base);
            for (int j = 0; j < cnt; j++) {
                int cc = __shfl(c, j);
                float vv = __shfl(v, j);
                a += vv * src[(size_t)cc * 64 + lane];
            }
        }
        a += bias[lane];
        if (RELU) a = fmaxf(a, 0.f);
        dst[(size_t)row * 64 + lane] = a;
    }
}

// ---------------- Pair scorer: out = relu([src,dst,src*dst] @ Wp1 + bp1) @ Wp2 + bp2 ----------------

__global__ __launch_bounds__(256) void pair_kernel(const int* __restrict__ pairs,
                                                   const float* __restrict__ z,
                                                   const float* __restrict__ Wp1,
                                                   const float* __restrict__ bp1,
                                                   const float* __restrict__ Wp2,
                                                   const float* __restrict__ bp2,
                                                   float* __restrict__ out) {
    __shared__ float As[32][33];
    __shared__ float Ws[32][64];
    int t = threadIdx.x;
    int tx = t & 15, ty = t >> 4;
    int row0 = blockIdx.x * 32;
    const int* p0s = pairs;
    const int* p1s = pairs + NPAIRS;
    float acc[2][4] = {};
    int lrow = t >> 3, lk0 = (t & 7) << 2;
    int rg = row0 + lrow;
    int p0 = p0s[rg], p1 = p1s[rg];
    for (int kc = 0; kc < 192; kc += 32) {
        float4 v;
        if (kc < 64) {
            v = *(const float4*)(z + (size_t)p0 * 64 + kc + lk0);
        } else if (kc < 128) {
            v = *(const float4*)(z + (size_t)p1 * 64 + (kc - 64) + lk0);
        } else {
            float4 a = *(const float4*)(z + (size_t)p0 * 64 + (kc - 128) + lk0);
            float4 b = *(const float4*)(z + (size_t)p1 * 64 + (kc - 128) + lk0);
            v = make_float4(a.x * b.x, a.y * b.y, a.z * b.z, a.w * b.w);
        }
        As[lrow][lk0 + 0] = v.x; As[lrow][lk0 + 1] = v.y;
        As[lrow][lk0 + 2] = v.z; As[lrow][lk0 + 3] = v.w;
#pragma unroll
        for (int l = 0; l < 2; l++) {
            int idx = l * 1024 + t * 4;
            int kk = idx >> 6, c = idx & 63;
            *(float4*)&Ws[kk][c] = *(const float4*)(Wp1 + (size_t)(kc + kk) * 64 + c);
        }
        __syncthreads();
#pragma unroll
        for (int kk = 0; kk < 32; kk++) {
            float4 w = *(const float4*)&Ws[kk][tx * 4];
#pragma unroll
            for (int i = 0; i < 2; i++) {
                float a = As[ty + 16 * i][kk];
                acc[i][0] += a * w.x; acc[i][1] += a * w.y;
                acc[i][2] += a * w.z; acc[i][3] += a * w.w;
            }
        }
        __syncthreads();
    }
    float b0 = bp1[tx * 4], b1v = bp1[tx * 4 + 1], b2v = bp1[tx * 4 + 2], b3v = bp1[tx * 4 + 3];
    float w0 = Wp2[tx * 4], w1 = Wp2[tx * 4 + 1], w2 = Wp2[tx * 4 + 2], w3 = Wp2[tx * 4 + 3];
#pragma unroll
    for (int i = 0; i < 2; i++) {
        float p = fmaxf(acc[i][0] + b0, 0.f) * w0 + fmaxf(acc[i][1] + b1v, 0.f) * w1 +
                  fmaxf(acc[i][2] + b2v, 0.f) * w2 + fmaxf(acc[i][3] + b3v, 0.f) * w3;
        p += __shfl_xor(p, 1);
        p += __shfl_xor(p, 2);
        p += __shfl_xor(p, 4);
        p += __shfl_xor(p, 8);
        if (tx == 0) out[row0 + ty + 16 * i] = p + bp2[0];
    }
}

// ---------------- launch ----------------

extern "C" void kernel_launch(void* const* d_in, const int* in_sizes, int n_in,
                              void* d_out, int out_size, void* d_ws, size_t ws_size,
                              hipStream_t stream) {
    const int*   tids     = (const int*)d_in[0];
    const int*   adj_rows = (const int*)d_in[1];
    const int*   adj_cols = (const int*)d_in[2];
    const float* adj_vals = (const float*)d_in[3];
    const int*   pairs    = (const int*)d_in[4];
    const float* node_emb = (const float*)d_in[5];
    const float* type_emb = (const float*)d_in[6];
    const float* W1  = (const float*)d_in[7];
    const float* b1  = (const float*)d_in[8];
    const float* W2  = (const float*)d_in[9];
    const float* b2  = (const float*)d_in[10];
    const float* Wp1 = (const float*)d_in[11];
    const float* bp1 = (const float*)d_in[12];
    const float* Wp2 = (const float*)d_in[13];
    const float* bp2 = (const float*)d_in[14];
    float* out = (float*)d_out;

    int n = in_sizes[0];
    int e = in_sizes[1];
    int p = in_sizes[4] / 2;

    char* ws = (char*)d_ws;
    float* bufA   = (float*)ws;                       // y, then g
    float* bufB   = bufA + (size_t)n * 128;           // h, then z
    int* row_ptr  = (int*)(bufB + (size_t)n * 128);   // n+1
    int* cursor   = row_ptr + (n + 1);                // n (counts, then cursors)
    int* blksum   = cursor + n;                       // 256
    int* csr_col  = blksum + 256;                     // e
    float* csr_val = (float*)(csr_col + e);           // e

    int eg = (e + 255) / 256;
    int nb = (n + 255) / 256;

    hipMemsetAsync(cursor, 0, (size_t)n * 4, stream);
    hist_kernel<<<eg, 256, 0, stream>>>(adj_rows, cursor, e);
    scan_block_kernel<<<nb, 256, 0, stream>>>(cursor, row_ptr, blksum, n);
    scan_sums_kernel<<<1, 256, 0, stream>>>(blksum, nb);
    scan_add_kernel<<<nb, 256, 0, stream>>>(row_ptr, blksum, cursor, n, e);
    scatter_kernel<<<eg, 256, 0, stream>>>(adj_rows, adj_cols, adj_vals, cursor, csr_col, csr_val, e);

    gemm1_kernel<<<(n + 31) / 32, 256, 0, stream>>>(node_emb, type_emb, tids, W1, bufA);
    spmm_kernel<128, true><<<(n + 3) / 4, 256, 0, stream>>>(row_ptr, csr_col, csr_val, bufA, b1, bufB);
    gemm2_kernel<<<(n + 63) / 64, 256, 0, stream>>>(bufB, W2, bufA);
    spmm_kernel<64, false><<<(n + 3) / 4, 256, 0, stream>>>(row_ptr, csr_col, csr_val, bufA, b2, bufB);
    pair_kernel<<<p / 32, 256, 0, stream>>>(pairs, bufB, Wp1, bp1, Wp2, bp2, out);
}